// Round 11
// baseline (101.408 us; speedup 1.0000x reference)
//
#include <hip/hip_runtime.h>

#define NALL 1024
#define NH   512
#define NCOL 8
#define ROWS_PER_BLOCK 64
#define THREADS 256
#define CHUNKS (NALL / ROWS_PER_BLOCK)   // 16
#define SAMPLES 1                        // A/B vs R10: one sample per block, grid 2048

typedef float f32x4 __attribute__((ext_vector_type(4)));

// R10 structure with SAMPLES=1 (grid 2048): tests grid-size/occupancy vs
// prologue-amortization now that nt loads are in. In the no-nt pair
// (R3 vs R9), grid 2048 beat 1024 by 12.7 us — more blocks/CU -> more
// memory-level parallelism and smoother tail; prologue redundancy is cheap.
// out[b][q*8+c], q = ih + 2*jh:
//   q0 = uJu (i<512, j<512),  q1 = vJu (i>=512, j<512),
//   q2 = uJv (i<512, j>=512), q3 = vJv (i>=512, j>=512)
__global__ __launch_bounds__(THREADS) void jxy_kernel(
    const float* __restrict__ x, const float* __restrict__ u,
    const float* __restrict__ v, float* __restrict__ out) {
    const int bid   = blockIdx.x;
    const int pair  = bid >> 4;          // sample index (SAMPLES=1)
    const int chunk = bid & (CHUNKS - 1);
    const int r0    = chunk * ROWS_PER_BLOCK;
    const int ih    = (r0 >= NH) ? 1 : 0;   // 64-row chunks never straddle halves
    const int rloc  = r0 - ih * NH;

    const int tid  = threadIdx.x;
    const int wave = tid >> 6;
    const int lane = tid & 63;
    const int jbase = wave * 256 + lane * 4;   // this lane's 4 fixed j positions
    const int jh    = (jbase >= NH) ? 1 : 0;   // uniform per wave
    const int jloc  = jbase - jh * NH;

    // ---- phase 1: joint column norms of concat(u,v) ----
    __shared__ float red[THREADS];
    __shared__ float inv_norm[NCOL];
    {
        const int c   = tid & 7;
        const int seg = tid >> 3;    // 0..31
        float s = 0.f;
        for (int r = seg; r < NH; r += 32) {
            float a = u[r * NCOL + c];
            float bb = v[r * NCOL + c];
            s = fmaf(a, a, fmaf(bb, bb, s));
        }
        red[tid] = s;
        __syncthreads();
        for (int off = THREADS / 2; off >= NCOL; off >>= 1) {
            if (tid < off) red[tid] += red[tid + off];
            __syncthreads();
        }
        if (tid < NCOL) inv_norm[tid] = 1.0f / sqrtf(red[tid]);
        __syncthreads();
    }

    // ---- phase 2: stage normalized left rows (LDS) + right fragment (regs) ----
    __shared__ __align__(16) float wl[ROWS_PER_BLOCK * NCOL];
    const float* rawl = ih ? v : u;
    for (int idx = tid; idx < ROWS_PER_BLOCK * NCOL; idx += THREADS)
        wl[idx] = rawl[rloc * NCOL + idx] * inv_norm[idx & 7];

    const float* rawr = jh ? v : u;
    float wr[4][NCOL];
#pragma unroll
    for (int k = 0; k < 4; ++k) {
        const float4* p = reinterpret_cast<const float4*>(rawr + (size_t)(jloc + k) * NCOL);
        float4 a = p[0];
        float4 bq = p[1];
        wr[k][0] = a.x * inv_norm[0];  wr[k][1] = a.y * inv_norm[1];
        wr[k][2] = a.z * inv_norm[2];  wr[k][3] = a.w * inv_norm[3];
        wr[k][4] = bq.x * inv_norm[4]; wr[k][5] = bq.y * inv_norm[5];
        wr[k][6] = bq.z * inv_norm[6]; wr[k][7] = bq.w * inv_norm[7];
    }
    __syncthreads();

    // ---- phase 3+4 per sample: stream 64 rows, reduce, one atomic set ----
    for (int s = 0; s < SAMPLES; ++s) {
        const int b = pair * SAMPLES + s;

        float acc[NCOL];
#pragma unroll
        for (int c = 0; c < NCOL; ++c) acc[c] = 0.f;

        const float* xrow = x + ((size_t)b * NALL + r0) * NALL + jbase;

#pragma unroll 8
        for (int r = 0; r < ROWS_PER_BLOCK; ++r) {
            f32x4 xv = __builtin_nontemporal_load(
                reinterpret_cast<const f32x4*>(xrow + (size_t)r * NALL));

            float t[NCOL];
#pragma unroll
            for (int c = 0; c < NCOL; ++c)
                t[c] = fmaf(xv.x, wr[0][c],
                       fmaf(xv.y, wr[1][c],
                       fmaf(xv.z, wr[2][c],
                            xv.w * wr[3][c])));

            // wave-uniform broadcast reads from LDS (no bank conflict)
            float4 wa = *reinterpret_cast<const float4*>(&wl[r * NCOL]);
            float4 wb = *reinterpret_cast<const float4*>(&wl[r * NCOL + 4]);
            acc[0] = fmaf(wa.x, t[0], acc[0]);
            acc[1] = fmaf(wa.y, t[1], acc[1]);
            acc[2] = fmaf(wa.z, t[2], acc[2]);
            acc[3] = fmaf(wa.w, t[3], acc[3]);
            acc[4] = fmaf(wb.x, t[4], acc[4]);
            acc[5] = fmaf(wb.y, t[5], acc[5]);
            acc[6] = fmaf(wb.z, t[6], acc[6]);
            acc[7] = fmaf(wb.w, t[7], acc[7]);
        }

        // wave butterfly reduce (8 values x 6 steps)
#pragma unroll
        for (int c = 0; c < NCOL; ++c) {
#pragma unroll
            for (int off = 32; off >= 1; off >>= 1)
                acc[c] += __shfl_xor(acc[c], off, 64);
        }

        if (lane == 0) {
            const int q = ih + 2 * jh;
            float* o = out + (size_t)b * (4 * NCOL) + q * NCOL;
#pragma unroll
            for (int c = 0; c < NCOL; ++c)
                atomicAdd(o + c, acc[c]);
        }
    }
}

extern "C" void kernel_launch(void* const* d_in, const int* in_sizes, int n_in,
                              void* d_out, int out_size, void* d_ws, size_t ws_size,
                              hipStream_t stream) {
    const float* x = (const float*)d_in[0];
    const float* u = (const float*)d_in[1];
    const float* v = (const float*)d_in[2];
    float* out = (float*)d_out;

    const int b_count = in_sizes[0] / (NALL * NALL);   // 128

    // zero the accumulated output every call (atomics accumulate into it)
    (void)hipMemsetAsync(d_out, 0, (size_t)out_size * sizeof(float), stream);

    dim3 grid((b_count / SAMPLES) * CHUNKS);   // 2048
    jxy_kernel<<<grid, THREADS, 0, stream>>>(x, u, v, out);
}

// Round 12
// 87.622 us; speedup vs baseline: 1.1573x; 1.1573x over previous
//
#include <hip/hip_runtime.h>

#define NALL 1024
#define NH   512
#define NCOL 8
#define THREADS 1024          // 16 waves
#define ROWS_PER_WAVE 128

typedef float f32x4 __attribute__((ext_vector_type(4)));

// Block = (sample b, i-half ih). grid = 256 = exactly 1 block/CU (16 waves/CU,
// same occupancy as the 95.2us R10 config; inner loop instruction-identical).
// Wave w: row-group wg=w>>2 (128 rows), j-quarter jq=w&3 (256 cols). Final
// cross-wave reduce in LDS -> block exclusively owns out[b][{ih, ih+2}*8+c]:
// plain stores, NO atomics, NO memset, prologue paid once per CU.
// out[b][q*8+c], q = ih + 2*jh.
__global__ __launch_bounds__(THREADS) void jxy_kernel(
    const float* __restrict__ x, const float* __restrict__ u,
    const float* __restrict__ v, float* __restrict__ out) {
    const int bid = blockIdx.x;
    const int b   = bid >> 1;
    const int ih  = bid & 1;
    const int r0  = ih * NH;

    const int tid  = threadIdx.x;
    const int wave = tid >> 6;
    const int lane = tid & 63;
    const int wg   = wave >> 2;              // row group 0..3
    const int jq   = wave & 3;               // j quarter 0..3
    const int jh   = jq >> 1;                // uniform per wave
    const int jbase = jq * 256 + lane * 4;
    const int jloc  = (jq & 1) * 256 + lane * 4;

    // ---- phase 1: joint column norms of concat(u,v) ----
    __shared__ float red[THREADS];
    __shared__ float inv_norm[NCOL];
    {
        const int c   = tid & 7;
        const int seg = tid >> 3;    // 0..127
        float s = 0.f;
        for (int r = seg; r < NH; r += 128) {
            float a = u[r * NCOL + c];
            float bb = v[r * NCOL + c];
            s = fmaf(a, a, fmaf(bb, bb, s));
        }
        red[tid] = s;
        __syncthreads();
        for (int off = THREADS / 2; off >= NCOL; off >>= 1) {
            if (tid < off) red[tid] += red[tid + off];
            __syncthreads();
        }
        if (tid < NCOL) inv_norm[tid] = 1.0f / sqrtf(red[tid]);
        __syncthreads();
    }

    // ---- phase 2: stage normalized left rows (16 KB LDS) + right frag (regs) ----
    __shared__ __align__(16) float wl[NH * NCOL];
    const float* rawl = ih ? v : u;
    for (int idx = tid; idx < NH * NCOL; idx += THREADS)
        wl[idx] = rawl[idx] * inv_norm[idx & 7];

    const float* rawr = jh ? v : u;
    float wr[4][NCOL];
#pragma unroll
    for (int k = 0; k < 4; ++k) {
        const float4* p = reinterpret_cast<const float4*>(rawr + (size_t)(jloc + k) * NCOL);
        float4 a = p[0];
        float4 bq = p[1];
        wr[k][0] = a.x * inv_norm[0];  wr[k][1] = a.y * inv_norm[1];
        wr[k][2] = a.z * inv_norm[2];  wr[k][3] = a.w * inv_norm[3];
        wr[k][4] = bq.x * inv_norm[4]; wr[k][5] = bq.y * inv_norm[5];
        wr[k][6] = bq.z * inv_norm[6]; wr[k][7] = bq.w * inv_norm[7];
    }
    __syncthreads();

    // ---- phase 3: stream this wave's 128 rows x 1 KB (nt, unroll 8) ----
    float acc[NCOL];
#pragma unroll
    for (int c = 0; c < NCOL; ++c) acc[c] = 0.f;

    const int rw = wg * ROWS_PER_WAVE;        // first row (within half) for this wave
    const float* xrow = x + ((size_t)b * NALL + r0 + rw) * NALL + jbase;
    const float* wlw  = &wl[rw * NCOL];

#pragma unroll 8
    for (int r = 0; r < ROWS_PER_WAVE; ++r) {
        f32x4 xv = __builtin_nontemporal_load(
            reinterpret_cast<const f32x4*>(xrow + (size_t)r * NALL));

        float t[NCOL];
#pragma unroll
        for (int c = 0; c < NCOL; ++c)
            t[c] = fmaf(xv.x, wr[0][c],
                   fmaf(xv.y, wr[1][c],
                   fmaf(xv.z, wr[2][c],
                        xv.w * wr[3][c])));

        // wave-uniform broadcast reads from LDS (no bank conflict)
        float4 wa = *reinterpret_cast<const float4*>(&wlw[r * NCOL]);
        float4 wb = *reinterpret_cast<const float4*>(&wlw[r * NCOL + 4]);
        acc[0] = fmaf(wa.x, t[0], acc[0]);
        acc[1] = fmaf(wa.y, t[1], acc[1]);
        acc[2] = fmaf(wa.z, t[2], acc[2]);
        acc[3] = fmaf(wa.w, t[3], acc[3]);
        acc[4] = fmaf(wb.x, t[4], acc[4]);
        acc[5] = fmaf(wb.y, t[5], acc[5]);
        acc[6] = fmaf(wb.z, t[6], acc[6]);
        acc[7] = fmaf(wb.w, t[7], acc[7]);
    }

    // ---- phase 4: wave butterfly, then cross-wave LDS reduce, plain store ----
#pragma unroll
    for (int c = 0; c < NCOL; ++c) {
#pragma unroll
        for (int off = 32; off >= 1; off >>= 1)
            acc[c] += __shfl_xor(acc[c], off, 64);
    }

    __shared__ float part[16][NCOL];
    if (lane == 0) {
#pragma unroll
        for (int c = 0; c < NCOL; ++c) part[wave][c] = acc[c];
    }
    __syncthreads();

    // 16 outputs owned by this block: (jh_sel in {0,1}) x (c in 0..7)
    if (tid < 16) {
        const int jh_sel = tid >> 3;
        const int c      = tid & 7;
        float s = 0.f;
        // waves with (w&3)>>1 == jh_sel: w&3 in {2*jh_sel, 2*jh_sel+1}
#pragma unroll
        for (int wgi = 0; wgi < 4; ++wgi) {
#pragma unroll
            for (int jqi = 0; jqi < 2; ++jqi)
                s += part[wgi * 4 + jh_sel * 2 + jqi][c];
        }
        const int q = ih + 2 * jh_sel;
        out[(size_t)b * (4 * NCOL) + q * NCOL + c] = s;
    }
}

extern "C" void kernel_launch(void* const* d_in, const int* in_sizes, int n_in,
                              void* d_out, int out_size, void* d_ws, size_t ws_size,
                              hipStream_t stream) {
    const float* x = (const float*)d_in[0];
    const float* u = (const float*)d_in[1];
    const float* v = (const float*)d_in[2];
    float* out = (float*)d_out;

    const int b_count = in_sizes[0] / (NALL * NALL);   // 128

    dim3 grid(b_count * 2);   // 256 = (sample, i-half); every output element
                              // written by exactly one block -> no memset needed
    jxy_kernel<<<grid, THREADS, 0, stream>>>(x, u, v, out);
}